// Round 13
// baseline (351.701 us; speedup 1.0000x reference)
//
#include <hip/hip_runtime.h>
#include <stdint.h>

// B=4, C=256, H=W=64, N=4096, CQK=16, Ktot=C*9=2304
// ws layout:
//   qT  [4][4096][64] bf16   @ 0     (2 MiB)  slots0-31=[qh|qh], 32-63=[ql|0], q pre-scaled by log2(e)
//   kT  [4][4096][32] bf16   @ 2 MiB (1 MiB)  slots0-15=kh, 16-31=kl (residual)
//   VF  [4][128][16][512] bf16 @ 3 MiB (8 MiB) V in MFMA-fragment order:
//        [b][J=j>>5][cblk=c>>4][g=(j>>3)&3][ln=c&15][e=j&7] -> attn av load = 1KB coalesced
//   W3v [4][18][256][32] bf16 @ 11 MiB (1152 KiB)  k-major: per-(chunk,ks) 512B coalesced block
//   W3q [4][18][16][32]  bf16 @ +1179648 (72 KiB)
//   W3k [4][18][16][32]  bf16 @ +73728   (72 KiB)

typedef __bf16 bf16;
typedef bf16 bf16x8 __attribute__((ext_vector_type(8)));
typedef float f32x4 __attribute__((ext_vector_type(4)));
typedef unsigned long long ull;

#define DEV static __device__ __forceinline__

DEV f32x4 mfma16(bf16x8 a, bf16x8 b, f32x4 c) {
  return __builtin_amdgcn_mfma_f32_16x16x32_bf16(a, b, c, 0, 0, 0);
}

// ===================== weight pack (all 3 tensors, one launch) =====================
// dst layout [chunk][ks 18][O][32]: conv A-frag read ((chunk*18+ks)*O + o)*32 + g*8 is
// one contiguous 512B segment per wave instruction (was 16 rows x 4608B stride).
__global__ void pack_all_kernel(const float* __restrict__ wv, const float* __restrict__ wq,
                                const float* __restrict__ wk, bf16* __restrict__ W3v,
                                bf16* __restrict__ W3q, bf16* __restrict__ W3k) {
  int idx = blockIdx.x * 256 + threadIdx.x;
  if (idx >= 663552) return;
  const float* src;
  bf16* dst;
  int rel, O;
  if (idx < 589824)      { src = wv; dst = W3v; rel = idx; O = 256; }
  else if (idx < 626688) { src = wq; dst = W3q; rel = idx - 589824; O = 16; }
  else                   { src = wk; dst = W3k; rel = idx - 626688; O = 16; }
  int o = rel / 2304, r = rel - o * 2304;
  int ci = r / 9, tap = r - ci * 9;
  int chunk = ci >> 6, c6 = ci & 63;
  int ks = (tap << 1) + (c6 >> 5), j = c6 & 31;
  dst[((chunk * 18 + ks) * O + o) * 32 + j] = (bf16)src[rel];
}

// ===================== conv staging (shared, b64 cl-quad writes) =====================
// LDS tile: [dh 0..2][wHalo 0..65][cl 0..63] bf16, byte ^ ((wH&7)<<4) swizzle.
// Thread (wg=t&15, clq=t>>4): per dh loads 4 float4 (cl=clq*4+cc, w=wg*4..+3),
// transposes in regs, writes 4 ds_write_b64 (4 consecutive cl each) — 4x fewer LDS ops.
DEV void stage_chunk(char* smc, const float* __restrict__ img, int b, int h, int ci0, int t) {
  if (t < 96) {   // halo zeros (wH = 0 and 65), b64 granularity
    int dh = t >> 5, r = t & 31;
    int wH = (r & 16) ? 65 : 0, cq = r & 15;
    *(ull*)(smc + ((((dh * 66 + wH) << 7) + (cq << 3)) ^ ((wH & 7) << 4))) = 0ull;
  }
  const int wg = t & 15, clq = t >> 4;   // w-quad, cl-quad
  for (int dh = 0; dh < 3; ++dh) {
    int hh = h + dh - 1;
    bool ok = (hh >= 0) && (hh < 64);
    float xs[4][4];
#pragma unroll
    for (int cc = 0; cc < 4; ++cc) {
      float4 xv = make_float4(0.f, 0.f, 0.f, 0.f);
      if (ok) xv = *(const float4*)&img[((((size_t)b << 8) + ci0 + (clq << 2) + cc) * 64 + hh) * 64 + (wg << 2)];
      xs[cc][0] = xv.x; xs[cc][1] = xv.y; xs[cc][2] = xv.z; xs[cc][3] = xv.w;
    }
#pragma unroll
    for (int q4 = 0; q4 < 4; ++q4) {
      int wH = (wg << 2) + q4 + 1;
      union { bf16 hh4[4]; ull v; } pk;
#pragma unroll
      for (int cc = 0; cc < 4; ++cc) pk.hh4[cc] = (bf16)xs[cc][q4];
      *(ull*)(smc + ((((dh * 66 + wH) << 7) + (clq << 3)) ^ ((wH & 7) << 4))) = pk.v;
    }
  }
}

// ===================== conv q + k fused (O=16) =====================
// grid 512: blocks 0-255 q-mode (img=x, scale log2e, qT 64-wide), 256-511 k-mode (img=y, kT 32-wide)
__global__ __launch_bounds__(256) void conv_qk_kernel(
    const float* __restrict__ x, const float* __restrict__ y,
    const bf16* __restrict__ W3q, const bf16* __restrict__ W3k,
    const float* __restrict__ bq, const float* __restrict__ bk,
    bf16* __restrict__ qT, bf16* __restrict__ kT) {
  __shared__ __align__(16) bf16 sm[3 * 66 * 64];
  const int mode = blockIdx.x >> 8;       // 0=q, 1=k
  const float* img = mode ? y : x;
  const bf16* W3 = mode ? W3k : W3q;
  const float* bias = mode ? bk : bq;
  const int bi = blockIdx.x & 255;
  const int t = threadIdx.x;
  const int lane = t & 63, wv = t >> 6;
  const int g = lane >> 4, ln = lane & 15;
  const int b = bi >> 6;
  const int h = bi & 63;
  f32x4 acc = {0.f, 0.f, 0.f, 0.f};
  for (int chunk = 0; chunk < 4; ++chunk) {
    __syncthreads();
    stage_chunk((char*)sm, img, b, h, chunk << 6, t);
    __syncthreads();
#pragma unroll
    for (int ks = 0; ks < 18; ++ks) {
      const int tap = ks >> 1, clb = (ks & 1) << 5;
      const int kh = tap / 3, kw = tap - kh * 3;
      const int wH = (wv << 4) + ln + kw;
      uint32_t bo = ((((kh * 66 + wH) << 6) + clb + (g << 3)) << 1) ^ ((wH & 7) << 4);
      bf16x8 bfr = *(const bf16x8*)((char*)sm + bo);
      bf16x8 afr = *(const bf16x8*)&W3[(size_t)((chunk * 18 + ks) * 16 + ln) * 32 + (g << 3)];
      acc = mfma16(afr, bfr, acc);
    }
  }
  const int p = (h << 6) + (wv << 4) + ln;
#pragma unroll
  for (int r = 0; r < 4; ++r) {
    int o = (g << 2) + r;
    float val = acc[r] + bias[o];
    if (mode == 0) {
      val *= 1.4426950408889634f;              // log2(e): softmax via exp2
      bf16* drow = qT + (((size_t)b << 12) + p) * 64;
      bf16 hi = (bf16)val;
      drow[o] = hi;
      drow[16 + o] = hi;                       // B1 = [qh|qh]
      drow[32 + o] = (bf16)(val - (float)hi);  // B2 = [ql|0]
      drow[48 + o] = (bf16)0.f;
    } else {
      bf16* drow = kT + (((size_t)b << 12) + p) * 32;
      bf16 hi = (bf16)val;
      drow[o] = hi;                            // A = [kh|kl]
      drow[16 + o] = (bf16)(val - (float)hi);
    }
  }
}

// ===================== conv v (O=256) -> VF fragment layout =====================
__global__ __launch_bounds__(256) void conv_v_kernel(
    const float* __restrict__ img, const bf16* __restrict__ W3,
    const float* __restrict__ bias, bf16* __restrict__ VF) {
  __shared__ __align__(16) bf16 sm[3 * 66 * 64];
  const int t = threadIdx.x;
  const int lane = t & 63, wv = t >> 6;
  const int g = lane >> 4, ln = lane & 15;
  const int raw = blockIdx.x;
  const int b = raw >> 7;
  const int h = (raw >> 1) & 63;
  const int oh = raw & 1;
  const int obase = (oh << 7) + (wv << 5);
  f32x4 acc[2][4];
#pragma unroll
  for (int of = 0; of < 2; ++of)
#pragma unroll
    for (int wf = 0; wf < 4; ++wf) acc[of][wf] = (f32x4){0.f, 0.f, 0.f, 0.f};
  for (int chunk = 0; chunk < 4; ++chunk) {
    __syncthreads();
    stage_chunk((char*)sm, img, b, h, chunk << 6, t);
    __syncthreads();
#pragma unroll
    for (int ks = 0; ks < 18; ++ks) {
      const int tap = ks >> 1, clb = (ks & 1) << 5;
      const int kh = tap / 3, kw = tap - kh * 3;
      bf16x8 bfr[4];
#pragma unroll
      for (int wf = 0; wf < 4; ++wf) {
        int wH = (wf << 4) + ln + kw;
        uint32_t bo = ((((kh * 66 + wH) << 6) + clb + (g << 3)) << 1) ^ ((wH & 7) << 4);
        bfr[wf] = *(const bf16x8*)((char*)sm + bo);
      }
#pragma unroll
      for (int of = 0; of < 2; ++of) {
        bf16x8 afr = *(const bf16x8*)&W3[(size_t)((chunk * 18 + ks) * 256 + obase + (of << 4) + ln) * 32 + (g << 3)];
#pragma unroll
        for (int wf = 0; wf < 4; ++wf) acc[of][wf] = mfma16(afr, bfr[wf], acc[of][wf]);
      }
    }
  }
  // epilogue -> VF[b][J][cblk][g][ln][e]: J=p>>5, gv=(p>>3)&3, e=p&7, cblk=c>>4, lnv=c&15
#pragma unroll
  for (int of = 0; of < 2; ++of) {
    const int cblk = (obase >> 4) + of;
#pragma unroll
    for (int r = 0; r < 4; ++r) {
      int c = obase + (of << 4) + (g << 2) + r;
      int lnv = c & 15;
      float bvv = bias[c];
#pragma unroll
      for (int wf = 0; wf < 4; ++wf) {
        int p = (h << 6) + (wf << 4) + ln;
        int J = p >> 5, gv = (p >> 3) & 3, e = p & 7;
        VF[(((size_t)(((b << 7) + J) << 4) + cblk) << 9) + (gv << 7) + (lnv << 3) + e] =
            (bf16)(acc[of][wf][r] + bvv);
      }
    }
  }
}

// ===================== attention =====================
// r13: grid 512 = (it 0..63, ch 0..1, b 0..3) [raw = it*8+ch*4+b; XCD=raw%8 in {b,b+4}].
// i-tile 64, ch-half 128 channels, KVBLK=128 (32 iters, 1 raw s_barrier per sub-iter).
// 8 waves: 0-3 producers (f=wv: QK from K-LDS, exp2, P->LDS dbuf, K staging);
// 4-7 consumers (32 ch each): ping-pong V prefetch from VF (1KB fully-coalesced loads),
// PV over 4 f. RAW s_barrier (no vmcnt drain!) + producer lgkmcnt(0); consumer V waits
// are compiler-counted vmcnt -> loads genuinely span barriers (fixes r10/r12's ~2850
// cyc/jt stall floor). 2 blocks/CU (4 waves/SIMD). Raw exp2 (no max): |s*log2e|<<127.
__global__ __launch_bounds__(512, 4) void attn_kernel(
    const bf16* __restrict__ qT, const bf16* __restrict__ kT,
    const bf16* __restrict__ VF, float* __restrict__ outp) {
  __shared__ __align__(16) char Klds[2 * 8192];    // [buf][row 128][64B] swizzled
  __shared__ __align__(16) char Plds[2 * 16384];   // [buf][f 4][ln 16][256B] swizzled
  __shared__ float lsumS[4][16];
  const int raw = blockIdx.x;          // 512
  const int b  = raw & 3;              // batch -> XCD pair {b, b+4}
  const int ch = (raw >> 2) & 1;       // channel half
  const int it = raw >> 3;             // 0..63
  const int i0 = it << 6;
  const int t = threadIdx.x;
  const int lane = t & 63, wv = t >> 6;
  const int g = lane >> 4, ln = lane & 15;
  const bool prod = (wv < 4);
  const int f = wv & 3;
  const int cb = (ch << 7) + (f << 5); // consumer: 32-channel base
  const int cblk0 = cb >> 4;

  const char* kTb = (const char*)kT + (((size_t)b << 12) << 6);  // 64B rows
  const char* vfb = (const char*)VF + ((size_t)b << 21);         // b * 2MB

  // producer state
  bf16x8 bq1 = {}, bq2 = {};
  if (prod) {
    const bf16* qrow = &qT[(((size_t)b << 12) + i0 + (f << 4) + ln) * 64];
    bq1 = *(const bf16x8*)&qrow[g << 3];
    bq2 = *(const bf16x8*)&qrow[32 + (g << 3)];
  }
  float lsum = 0.f;
  const int krow = t >> 1, khalf = t & 1;   // K-stage map (prod threads are exactly t 0..255)
  const uint32_t kw0 = ((uint32_t)krow << 6) + ((uint32_t)(((khalf << 1)) ^ (krow & 3)) << 4);
  const uint32_t kw1 = ((uint32_t)krow << 6) + ((uint32_t)(((khalf << 1) + 1) ^ (krow & 3)) << 4);

  // consumer state
  f32x4 acc[2][4];   // [cf][ff]
#pragma unroll
  for (int cf = 0; cf < 2; ++cf)
#pragma unroll
    for (int ff = 0; ff < 4; ++ff) acc[cf][ff] = (f32x4){0.f, 0.f, 0.f, 0.f};
  bf16x8 avA[8], avB[8];   // ping-pong V [ks*2+cf], static idx

  // prologue: producers stage K(0) -> buf0
  if (prod) {
    f32x4 k0 = *(const f32x4*)(kTb + ((size_t)krow << 6) + (khalf << 5));
    f32x4 k1 = *(const f32x4*)(kTb + ((size_t)krow << 6) + (khalf << 5) + 16);
    *(f32x4*)(Klds + kw0) = k0;
    *(f32x4*)(Klds + kw1) = k1;
    asm volatile("s_waitcnt lgkmcnt(0)" ::: "memory");
  }
  __builtin_amdgcn_s_barrier();
  __builtin_amdgcn_sched_barrier(0);

#define PROD_STEP(KB, PB, NXT_JT, NXT_KB, DO_STAGE)                                          \
  {                                                                                          \
    f32x4 kr0 = {}, kr1 = {};                                                                \
    if (DO_STAGE) {                                                                          \
      kr0 = *(const f32x4*)(kTb + (size_t)(((NXT_JT) << 7) + krow) * 64 + (khalf << 5));     \
      kr1 = *(const f32x4*)(kTb + (size_t)(((NXT_JT) << 7) + krow) * 64 + (khalf << 5) + 16);\
    }                                                                                        \
    _Pragma("unroll")                                                                        \
    for (int hh2 = 0; hh2 < 2; ++hh2) {                                                      \
      f32x4 s[4];                                                                            \
      _Pragma("unroll")                                                                      \
      for (int q = 0; q < 4; ++q) {                                                          \
        const int row = ((hh2 << 2) + q) * 16 + ln;                                          \
        bf16x8 ak = *(const bf16x8*)(Klds + (KB) + ((uint32_t)row << 6) +                    \
                                     ((uint32_t)(g ^ (row & 3)) << 4));                      \
        f32x4 z = {0.f, 0.f, 0.f, 0.f};                                                      \
        s[q] = mfma16(ak, bq2, mfma16(ak, bq1, z));                                          \
      }                                                                                      \
      _Pragma("unroll")                                                                      \
      for (int q = 0; q < 4; ++q) {                                                          \
        const int jf = (hh2 << 2) + q;                                                       \
        union { bf16 h4[4]; ull v; } pk;                                                     \
        _Pragma("unroll")                                                                    \
        for (int r = 0; r < 4; ++r) {                                                        \
          float pv = __builtin_amdgcn_exp2f(s[q][r]);                                        \
          lsum += pv;                                                                        \
          pk.h4[r] = (bf16)pv;                                                               \
        }                                                                                    \
        uint32_t bo = ((PB) + ((uint32_t)f << 12) + ((uint32_t)ln << 8) + (jf << 5) +        \
                       (g << 3)) ^ ((ln & 7) << 4);                                          \
        *(ull*)(Plds + bo) = pk.v;                                                           \
      }                                                                                      \
    }                                                                                        \
    if (DO_STAGE) {                                                                          \
      *(f32x4*)(Klds + (NXT_KB) + kw0) = kr0;                                                \
      *(f32x4*)(Klds + (NXT_KB) + kw1) = kr1;                                                \
    }                                                                                        \
    asm volatile("s_waitcnt lgkmcnt(0)" ::: "memory");                                       \
  }

#define CONS_LOAD(AV, JT)                                                                    \
  {                                                                                          \
    _Pragma("unroll")                                                                        \
    for (int ks = 0; ks < 4; ++ks)                                                           \
      _Pragma("unroll")                                                                      \
      for (int cf = 0; cf < 2; ++cf)                                                         \
        AV[ks * 2 + cf] = *(const bf16x8*)(vfb +                                             \
            ((size_t)((((JT) << 2) + ks) * 16 + cblk0 + cf) << 10) + (lane << 4));           \
  }

#define CONS_PV(AV, PB)                                                                      \
  {                                                                                          \
    __builtin_amdgcn_s_setprio(1);                                                           \
    _Pragma("unroll")                                                                        \
    for (int ks = 0; ks < 4; ++ks) {                                                         \
      _Pragma("unroll")                                                                      \
      for (int ff = 0; ff < 4; ++ff) {                                                       \
        uint32_t bo = ((PB) + ((uint32_t)ff << 12) + ((uint32_t)ln << 8) + (ks << 6) +       \
                       (g << 4)) ^ ((ln & 7) << 4);                                          \
        bf16x8 bp = *(const bf16x8*)(Plds + bo);                                             \
        acc[0][ff] = mfma16(AV[ks * 2 + 0], bp, acc[0][ff]);                                 \
        acc[1][ff] = mfma16(AV[ks * 2 + 1], bp, acc[1][ff]);                                 \
      }                                                                                      \
    }                                                                                        \
    __builtin_amdgcn_s_setprio(0);                                                           \
  }

  for (int m = 0; m < 16; ++m) {
    const int jtA = m << 1;
    // ---------- sub-iter A: prod computes P(jtA)->buf0, stages K(jtA+1)->buf1;
    //            cons loads V(jtA)->avB, computes PV(jtA-1) from buf1+avA ----------
    if (prod) {
      PROD_STEP(0u, 0u, jtA + 1, 8192u, true)
    } else {
      CONS_LOAD(avB, jtA)
      if (m > 0) CONS_PV(avA, 16384u)
    }
    __builtin_amdgcn_s_barrier();
    __builtin_amdgcn_sched_barrier(0);
    // ---------- sub-iter B: prod P(jtA+1)->buf1, stages K(jtA+2)->buf0;
    //            cons loads V(jtA+1)->avA, computes PV(jtA) from buf0+avB ----------
    if (prod) {
      PROD_STEP(8192u, 16384u, jtA + 2, 0u, (m < 15))
    } else {
      CONS_LOAD(avA, jtA + 1)
      CONS_PV(avB, 0u)
    }
    __builtin_amdgcn_s_barrier();
    __builtin_amdgcn_sched_barrier(0);
  }
  // epilogue: producers publish lsum; consumers final PV(31) (buf1 + avA)
  if (prod) {
    float l = lsum;
    l += __shfl_xor(l, 16, 64);
    l += __shfl_xor(l, 32, 64);
    if (g == 0) lsumS[f][ln] = l;
  } else {
    CONS_PV(avA, 16384u)
  }
  __syncthreads();
  if (!prod) {
#pragma unroll
    for (int ff = 0; ff < 4; ++ff) {
      float rdiv = 1.f / lsumS[ff][ln];
      const int i = i0 + (ff << 4) + ln;
#pragma unroll
      for (int cf = 0; cf < 2; ++cf)
#pragma unroll
        for (int r = 0; r < 4; ++r) {
          int c = cb + (cf << 4) + (g << 2) + r;
          outp[(((size_t)b << 8) + c) * 4096 + i] = acc[cf][ff][r] * rdiv;
        }
    }
  }
#undef PROD_STEP
#undef CONS_LOAD
#undef CONS_PV
}

// ===================== launch =====================
extern "C" void kernel_launch(void* const* d_in, const int* in_sizes, int n_in,
                              void* d_out, int out_size, void* d_ws, size_t ws_size,
                              hipStream_t stream) {
  const float* x  = (const float*)d_in[0];
  const float* y  = (const float*)d_in[1];
  const float* wq = (const float*)d_in[2];
  const float* bq = (const float*)d_in[3];
  const float* wk = (const float*)d_in[4];
  const float* bk = (const float*)d_in[5];
  const float* wv = (const float*)d_in[6];
  const float* bv = (const float*)d_in[7];
  float* out = (float*)d_out;

  char* ws = (char*)d_ws;
  bf16* qT  = (bf16*)(ws);
  bf16* kT  = (bf16*)(ws + (2u << 20));
  bf16* VF  = (bf16*)(ws + (3u << 20));
  bf16* W3v = (bf16*)(ws + (11u << 20));
  bf16* W3q = (bf16*)(ws + (11u << 20) + 1179648u);
  bf16* W3k = (bf16*)(ws + (11u << 20) + 1179648u + 73728u);

  pack_all_kernel<<<2592, 256, 0, stream>>>(wv, wq, wk, W3v, W3q, W3k);
  conv_qk_kernel<<<512, 256, 0, stream>>>(x, y, W3q, W3k, bq, bk, qT, kT);
  conv_v_kernel<<<512, 256, 0, stream>>>(y, W3v, bv, VF);
  attn_kernel<<<512, 512, 0, stream>>>(qT, kT, VF, out);
}

// Round 16
// 182.363 us; speedup vs baseline: 1.9286x; 1.9286x over previous
//
#include <hip/hip_runtime.h>
#include <stdint.h>

// B=4, C=256, H=W=64, N=4096, CQK=16, Ktot=C*9=2304
// ws layout:
//   qT  [4][4096][64] bf16   @ 0     (2 MiB)  slots0-31=[qh|qh], 32-63=[ql|0], q pre-scaled by log2(e)
//   kT  [4][4096][32] bf16   @ 2 MiB (1 MiB)  slots0-15=kh, 16-31=kl (residual)
//   VF  [4][128][16][512] bf16 @ 3 MiB (8 MiB) V in MFMA-fragment order:
//        [b][J=j>>5][cblk=c>>4][g=(j>>3)&3][ln=c&15][e=j&7] -> attn av load = 1KB coalesced
//   W3v [4][18][256][32] bf16 @ 11 MiB (1152 KiB)  k-major: per-(chunk,ks) 512B coalesced block
//   W3q [4][18][16][32]  bf16 @ +1179648 (72 KiB)
//   W3k [4][18][16][32]  bf16 @ +73728   (72 KiB)

typedef __bf16 bf16;
typedef bf16 bf16x8 __attribute__((ext_vector_type(8)));
typedef float f32x4 __attribute__((ext_vector_type(4)));
typedef unsigned long long ull;

#define DEV static __device__ __forceinline__

DEV f32x4 mfma16(bf16x8 a, bf16x8 b, f32x4 c) {
  return __builtin_amdgcn_mfma_f32_16x16x32_bf16(a, b, c, 0, 0, 0);
}

// ===================== weight pack (all 3 tensors, one launch) =====================
__global__ void pack_all_kernel(const float* __restrict__ wv, const float* __restrict__ wq,
                                const float* __restrict__ wk, bf16* __restrict__ W3v,
                                bf16* __restrict__ W3q, bf16* __restrict__ W3k) {
  int idx = blockIdx.x * 256 + threadIdx.x;
  if (idx >= 663552) return;
  const float* src;
  bf16* dst;
  int rel, O;
  if (idx < 589824)      { src = wv; dst = W3v; rel = idx; O = 256; }
  else if (idx < 626688) { src = wq; dst = W3q; rel = idx - 589824; O = 16; }
  else                   { src = wk; dst = W3k; rel = idx - 626688; O = 16; }
  int o = rel / 2304, r = rel - o * 2304;
  int ci = r / 9, tap = r - ci * 9;
  int chunk = ci >> 6, c6 = ci & 63;
  int ks = (tap << 1) + (c6 >> 5), j = c6 & 31;
  dst[((chunk * 18 + ks) * O + o) * 32 + j] = (bf16)src[rel];
}

// ===================== conv staging (shared, b64 cl-quad writes) =====================
DEV void stage_chunk(char* smc, const float* __restrict__ img, int b, int h, int ci0, int t) {
  if (t < 96) {   // halo zeros (wH = 0 and 65), b64 granularity
    int dh = t >> 5, r = t & 31;
    int wH = (r & 16) ? 65 : 0, cq = r & 15;
    *(ull*)(smc + ((((dh * 66 + wH) << 7) + (cq << 3)) ^ ((wH & 7) << 4))) = 0ull;
  }
  const int wg = t & 15, clq = t >> 4;   // w-quad, cl-quad
  for (int dh = 0; dh < 3; ++dh) {
    int hh = h + dh - 1;
    bool ok = (hh >= 0) && (hh < 64);
    float xs[4][4];
#pragma unroll
    for (int cc = 0; cc < 4; ++cc) {
      float4 xv = make_float4(0.f, 0.f, 0.f, 0.f);
      if (ok) xv = *(const float4*)&img[((((size_t)b << 8) + ci0 + (clq << 2) + cc) * 64 + hh) * 64 + (wg << 2)];
      xs[cc][0] = xv.x; xs[cc][1] = xv.y; xs[cc][2] = xv.z; xs[cc][3] = xv.w;
    }
#pragma unroll
    for (int q4 = 0; q4 < 4; ++q4) {
      int wH = (wg << 2) + q4 + 1;
      union { bf16 hh4[4]; ull v; } pk;
#pragma unroll
      for (int cc = 0; cc < 4; ++cc) pk.hh4[cc] = (bf16)xs[cc][q4];
      *(ull*)(smc + ((((dh * 66 + wH) << 7) + (clq << 3)) ^ ((wH & 7) << 4))) = pk.v;
    }
  }
}

// ===================== conv q + k fused (O=16) =====================
__global__ __launch_bounds__(256) void conv_qk_kernel(
    const float* __restrict__ x, const float* __restrict__ y,
    const bf16* __restrict__ W3q, const bf16* __restrict__ W3k,
    const float* __restrict__ bq, const float* __restrict__ bk,
    bf16* __restrict__ qT, bf16* __restrict__ kT) {
  __shared__ __align__(16) bf16 sm[3 * 66 * 64];
  const int mode = blockIdx.x >> 8;       // 0=q, 1=k
  const float* img = mode ? y : x;
  const bf16* W3 = mode ? W3k : W3q;
  const float* bias = mode ? bk : bq;
  const int bi = blockIdx.x & 255;
  const int t = threadIdx.x;
  const int lane = t & 63, wv = t >> 6;
  const int g = lane >> 4, ln = lane & 15;
  const int b = bi >> 6;
  const int h = bi & 63;
  f32x4 acc = {0.f, 0.f, 0.f, 0.f};
  for (int chunk = 0; chunk < 4; ++chunk) {
    __syncthreads();
    stage_chunk((char*)sm, img, b, h, chunk << 6, t);
    __syncthreads();
#pragma unroll
    for (int ks = 0; ks < 18; ++ks) {
      const int tap = ks >> 1, clb = (ks & 1) << 5;
      const int kh = tap / 3, kw = tap - kh * 3;
      const int wH = (wv << 4) + ln + kw;
      uint32_t bo = ((((kh * 66 + wH) << 6) + clb + (g << 3)) << 1) ^ ((wH & 7) << 4);
      bf16x8 bfr = *(const bf16x8*)((char*)sm + bo);
      bf16x8 afr = *(const bf16x8*)&W3[(size_t)((chunk * 18 + ks) * 16 + ln) * 32 + (g << 3)];
      acc = mfma16(afr, bfr, acc);
    }
  }
  const int p = (h << 6) + (wv << 4) + ln;
#pragma unroll
  for (int r = 0; r < 4; ++r) {
    int o = (g << 2) + r;
    float val = acc[r] + bias[o];
    if (mode == 0) {
      val *= 1.4426950408889634f;              // log2(e): softmax via exp2
      bf16* drow = qT + (((size_t)b << 12) + p) * 64;
      bf16 hi = (bf16)val;
      drow[o] = hi;
      drow[16 + o] = hi;                       // B1 = [qh|qh]
      drow[32 + o] = (bf16)(val - (float)hi);  // B2 = [ql|0]
      drow[48 + o] = (bf16)0.f;
    } else {
      bf16* drow = kT + (((size_t)b << 12) + p) * 32;
      bf16 hi = (bf16)val;
      drow[o] = hi;                            // A = [kh|kl]
      drow[16 + o] = (bf16)(val - (float)hi);
    }
  }
}

// ===================== conv v (O=256) -> VF fragment layout =====================
__global__ __launch_bounds__(256) void conv_v_kernel(
    const float* __restrict__ img, const bf16* __restrict__ W3,
    const float* __restrict__ bias, bf16* __restrict__ VF) {
  __shared__ __align__(16) bf16 sm[3 * 66 * 64];
  const int t = threadIdx.x;
  const int lane = t & 63, wv = t >> 6;
  const int g = lane >> 4, ln = lane & 15;
  const int raw = blockIdx.x;
  const int b = raw >> 7;
  const int h = (raw >> 1) & 63;
  const int oh = raw & 1;
  const int obase = (oh << 7) + (wv << 5);
  f32x4 acc[2][4];
#pragma unroll
  for (int of = 0; of < 2; ++of)
#pragma unroll
    for (int wf = 0; wf < 4; ++wf) acc[of][wf] = (f32x4){0.f, 0.f, 0.f, 0.f};
  for (int chunk = 0; chunk < 4; ++chunk) {
    __syncthreads();
    stage_chunk((char*)sm, img, b, h, chunk << 6, t);
    __syncthreads();
#pragma unroll
    for (int ks = 0; ks < 18; ++ks) {
      const int tap = ks >> 1, clb = (ks & 1) << 5;
      const int kh = tap / 3, kw = tap - kh * 3;
      bf16x8 bfr[4];
#pragma unroll
      for (int wf = 0; wf < 4; ++wf) {
        int wH = (wf << 4) + ln + kw;
        uint32_t bo = ((((kh * 66 + wH) << 6) + clb + (g << 3)) << 1) ^ ((wH & 7) << 4);
        bfr[wf] = *(const bf16x8*)((char*)sm + bo);
      }
#pragma unroll
      for (int of = 0; of < 2; ++of) {
        bf16x8 afr = *(const bf16x8*)&W3[(size_t)((chunk * 18 + ks) * 256 + obase + (of << 4) + ln) * 32 + (g << 3)];
#pragma unroll
        for (int wf = 0; wf < 4; ++wf) acc[of][wf] = mfma16(afr, bfr[wf], acc[of][wf]);
      }
    }
  }
  // epilogue -> VF[b][J][cblk][g][ln][e]
#pragma unroll
  for (int of = 0; of < 2; ++of) {
    const int cblk = (obase >> 4) + of;
#pragma unroll
    for (int r = 0; r < 4; ++r) {
      int c = obase + (of << 4) + (g << 2) + r;
      int lnv = c & 15;
      float bvv = bias[c];
#pragma unroll
      for (int wf = 0; wf < 4; ++wf) {
        int p = (h << 6) + (wf << 4) + ln;
        int J = p >> 5, gv = (p >> 3) & 3, e = p & 7;
        VF[(((size_t)(((b << 7) + J) << 4) + cblk) << 9) + (gv << 7) + (lnv << 3) + e] =
            (bf16)(acc[of][wf][r] + bvv);
      }
    }
  }
}

// ===================== attention =====================
// r14: r12's PROVEN schedule (producer/consumer, __syncthreads dbuf, launch_bounds(512,2),
// VGPR ~104 no spill) + ONE change: V loads from VF fragment layout -> each av load is
// one 1KB fully-coalesced segment (r12: 16 x 64B scatter, ~500-800 TA-cyc/CU-jt).
// grid 256 = (b, it 0..63), i-tile 64, 8 waves. Waves 0-3 producers (f=wv): QK from
// K-LDS, exp2, P->LDS(dbuf), K staging. Waves 4-7 consumers (64 ch): ping-pong V
// prefetch, PV over 4 f. Raw exp2 (no max). batch -> XCD pair {b, b+4}.
__global__ __launch_bounds__(512, 2) void attn_kernel(
    const bf16* __restrict__ qT, const bf16* __restrict__ kT,
    const bf16* __restrict__ VF, float* __restrict__ outp) {
  __shared__ __align__(16) char Klds[2 * 4096];   // [buf][row 64][64B] swizzled
  __shared__ __align__(16) char Plds[2 * 8192];   // [buf][f 4][ln 16][128B] swizzled
  __shared__ float lsumS[4][16];
  const int raw = blockIdx.x;          // 256
  const int b  = raw & 3;              // batch -> XCD pair {b, b+4}
  const int it = raw >> 2;             // 0..63
  const int i0 = it << 6;
  const int t = threadIdx.x;
  const int lane = t & 63, wv = t >> 6;
  const int g = lane >> 4, ln = lane & 15;
  const bool prod = (wv < 4);
  const int f = wv & 3;
  const int cb = f << 6;               // consumer: 64-channel base
  const int cblk0 = f << 2;            // = cb >> 4

  const char* kTb = (const char*)kT + (((size_t)b << 12) << 6);  // 64B rows
  const char* vfb = (const char*)VF + ((size_t)b << 21);         // b * 2MB

  // producer state
  bf16x8 bq1 = {}, bq2 = {};
  if (prod) {
    const bf16* qrow = &qT[(((size_t)b << 12) + i0 + (f << 4) + ln) * 64];
    bq1 = *(const bf16x8*)&qrow[g << 3];
    bq2 = *(const bf16x8*)&qrow[32 + (g << 3)];
  }
  float lsum = 0.f;
  const int krow = t >> 2, kc = t & 3;   // K-stage map (producers: t 0..255)
  const uint32_t kwoff = ((uint32_t)krow << 6) + ((uint32_t)(kc ^ (krow & 3)) << 4);

  // consumer state
  f32x4 acc[4][4];   // [cf][f]
#pragma unroll
  for (int cf = 0; cf < 4; ++cf)
#pragma unroll
    for (int ff = 0; ff < 4; ++ff) acc[cf][ff] = (f32x4){0.f, 0.f, 0.f, 0.f};
  bf16x8 avA[8], avB[8];   // ping-pong V prefetch [ks*4+cf]; static idx via unroll

  // prologue: producers stage K(0) -> buf0
  if (prod)
    *(f32x4*)(Klds + kwoff) = *(const f32x4*)(kTb + ((size_t)krow << 6) + (kc << 4));
  __syncthreads();

  for (int m = 0; m < 32; ++m) {
    const int jtA = m << 1;           // even jt
    // ---------- sub-iter A ----------
    if (prod) {
      f32x4 s[4];
#pragma unroll
      for (int jf = 0; jf < 4; ++jf) {
        const int row = (jf << 4) + ln;
        bf16x8 ak = *(const bf16x8*)(Klds + ((uint32_t)row << 6) + ((uint32_t)(g ^ (row & 3)) << 4));
        f32x4 z = {0.f, 0.f, 0.f, 0.f};
        s[jf] = mfma16(ak, bq2, mfma16(ak, bq1, z));
      }
#pragma unroll
      for (int jf = 0; jf < 4; ++jf) {
        union { bf16 h[4]; ull v; } pk;
#pragma unroll
        for (int r = 0; r < 4; ++r) {
          float pv = __builtin_amdgcn_exp2f(s[jf][r]);
          lsum += pv;
          pk.h[r] = (bf16)pv;
        }
        uint32_t bo = (((uint32_t)f << 11) + ((uint32_t)ln << 7) + (jf << 5) + (g << 3)) ^ ((ln & 7) << 4);
        *(ull*)(Plds + bo) = pk.v;            // P buf0
      }
      // stage K(jtA+1) -> buf1
      *(f32x4*)(Klds + 4096 + kwoff) =
          *(const f32x4*)(kTb + ((size_t)(((jtA + 1) << 6) + krow) << 6) + (kc << 4));
    } else {
#pragma unroll
      for (int ks = 0; ks < 2; ++ks)
#pragma unroll
        for (int cf = 0; cf < 4; ++cf)
          avB[ks * 4 + cf] = *(const bf16x8*)(vfb +
              ((size_t)(((jtA << 1) + ks) * 16 + cblk0 + cf) << 10) + (lane << 4));
      if (m > 0) {   // PV(jtA-1): P buf1, V in avA
        __builtin_amdgcn_s_setprio(1);
#pragma unroll
        for (int ks = 0; ks < 2; ++ks) {
          bf16x8 bp[4];
#pragma unroll
          for (int ff = 0; ff < 4; ++ff) {
            uint32_t bo = (8192u + ((uint32_t)ff << 11) + ((uint32_t)ln << 7) + (ks << 6) + (g << 4)) ^ ((ln & 7) << 4);
            bp[ff] = *(const bf16x8*)(Plds + bo);
          }
#pragma unroll
          for (int cf = 0; cf < 4; ++cf)
#pragma unroll
            for (int ff = 0; ff < 4; ++ff)
              acc[cf][ff] = mfma16(avA[ks * 4 + cf], bp[ff], acc[cf][ff]);
        }
        __builtin_amdgcn_s_setprio(0);
      }
    }
    __syncthreads();
    // ---------- sub-iter B ----------
    const int jtB = jtA + 1;          // odd jt
    if (prod) {
      f32x4 s[4];
#pragma unroll
      for (int jf = 0; jf < 4; ++jf) {
        const int row = (jf << 4) + ln;
        bf16x8 ak = *(const bf16x8*)(Klds + 4096 + ((uint32_t)row << 6) + ((uint32_t)(g ^ (row & 3)) << 4));
        f32x4 z = {0.f, 0.f, 0.f, 0.f};
        s[jf] = mfma16(ak, bq2, mfma16(ak, bq1, z));
      }
#pragma unroll
      for (int jf = 0; jf < 4; ++jf) {
        union { bf16 h[4]; ull v; } pk;
#pragma unroll
        for (int r = 0; r < 4; ++r) {
          float pv = __builtin_amdgcn_exp2f(s[jf][r]);
          lsum += pv;
          pk.h[r] = (bf16)pv;
        }
        uint32_t bo = (8192u + ((uint32_t)f << 11) + ((uint32_t)ln << 7) + (jf << 5) + (g << 3)) ^ ((ln & 7) << 4);
        *(ull*)(Plds + bo) = pk.v;            // P buf1
      }
      if (m < 31)   // stage K(jtB+1) -> buf0
        *(f32x4*)(Klds + kwoff) =
            *(const f32x4*)(kTb + ((size_t)(((jtB + 1) << 6) + krow) << 6) + (kc << 4));
    } else {
#pragma unroll
      for (int ks = 0; ks < 2; ++ks)
#pragma unroll
        for (int cf = 0; cf < 4; ++cf)
          avA[ks * 4 + cf] = *(const bf16x8*)(vfb +
              ((size_t)(((jtB << 1) + ks) * 16 + cblk0 + cf) << 10) + (lane << 4));
      // PV(jtA): P buf0, V in avB
      __builtin_amdgcn_s_setprio(1);
#pragma unroll
      for (int ks = 0; ks < 2; ++ks) {
        bf16x8 bp[4];
#pragma unroll
        for (int ff = 0; ff < 4; ++ff) {
          uint32_t bo = (((uint32_t)ff << 11) + ((uint32_t)ln << 7) + (ks << 6) + (g << 4)) ^ ((ln & 7) << 4);
          bp[ff] = *(const bf16x8*)(Plds + bo);
        }
#pragma unroll
        for (int cf = 0; cf < 4; ++cf)
#pragma unroll
          for (int ff = 0; ff < 4; ++ff)
            acc[cf][ff] = mfma16(avB[ks * 4 + cf], bp[ff], acc[cf][ff]);
      }
      __builtin_amdgcn_s_setprio(0);
    }
    __syncthreads();
  }
  // epilogue: producers publish lsum; consumers final PV(63) (P buf1, avA)
  if (prod) {
    float l = lsum;
    l += __shfl_xor(l, 16, 64);
    l += __shfl_xor(l, 32, 64);
    if (g == 0) lsumS[f][ln] = l;
  } else {
#pragma unroll
    for (int ks = 0; ks < 2; ++ks) {
      bf16x8 bp[4];
#pragma unroll
      for (int ff = 0; ff < 4; ++ff) {
        uint32_t bo = (8192u + ((uint32_t)ff << 11) + ((uint32_t)ln << 7) + (ks << 6) + (g << 4)) ^ ((ln & 7) << 4);
        bp[ff] = *(const bf16x8*)(Plds + bo);
      }
#pragma unroll
      for (int cf = 0; cf < 4; ++cf)
#pragma unroll
        for (int ff = 0; ff < 4; ++ff)
          acc[cf][ff] = mfma16(avA[ks * 4 + cf], bp[ff], acc[cf][ff]);
    }
  }
  __syncthreads();
  if (!prod) {
#pragma unroll
    for (int ff = 0; ff < 4; ++ff) {
      float rdiv = 1.f / lsumS[ff][ln];
      const int i = i0 + (ff << 4) + ln;
#pragma unroll
      for (int cf = 0; cf < 4; ++cf)
#pragma unroll
        for (int r = 0; r < 4; ++r) {
          int c = cb + (cf << 4) + (g << 2) + r;
          outp[(((size_t)b << 8) + c) * 4096 + i] = acc[cf][ff][r] * rdiv;
        }
    }
  }
}

// ===================== launch =====================
extern "C" void kernel_launch(void* const* d_in, const int* in_sizes, int n_in,
                              void* d_out, int out_size, void* d_ws, size_t ws_size,
                              hipStream_t stream) {
  const float* x  = (const float*)d_in[0];
  const float* y  = (const float*)d_in[1];
  const float* wq = (const float*)d_in[2];
  const float* bq = (const float*)d_in[3];
  const float* wk = (const float*)d_in[4];
  const float* bk = (const float*)d_in[5];
  const float* wv = (const float*)d_in[6];
  const float* bv = (const float*)d_in[7];
  float* out = (float*)d_out;

  char* ws = (char*)d_ws;
  bf16* qT  = (bf16*)(ws);
  bf16* kT  = (bf16*)(ws + (2u << 20));
  bf16* VF  = (bf16*)(ws + (3u << 20));
  bf16* W3v = (bf16*)(ws + (11u << 20));
  bf16* W3q = (bf16*)(ws + (11u << 20) + 1179648u);
  bf16* W3k = (bf16*)(ws + (11u << 20) + 1179648u + 73728u);

  pack_all_kernel<<<2592, 256, 0, stream>>>(wv, wq, wk, W3v, W3q, W3k);
  conv_qk_kernel<<<512, 256, 0, stream>>>(x, y, W3q, W3k, bq, bk, qT, kT);
  conv_v_kernel<<<512, 256, 0, stream>>>(y, W3v, bv, VF);
  attn_kernel<<<256, 512, 0, stream>>>(qT, kT, VF, out);
}

// Round 17
// 175.654 us; speedup vs baseline: 2.0022x; 1.0382x over previous
//
#include <hip/hip_runtime.h>
#include <stdint.h>

// B=4, C=256, H=W=64, N=4096, CQK=16, Ktot=C*9=2304
// ws layout:
//   qT  [4][4096][64] bf16   @ 0     (2 MiB)  slots0-31=[qh|qh], 32-63=[ql|0], q pre-scaled by log2(e)
//   kT  [4][4096][32] bf16   @ 2 MiB (1 MiB)  slots0-15=kh, 16-31=kl (residual)
//   VF  [4][128][16][512] bf16 @ 3 MiB (8 MiB) V in MFMA-fragment order:
//        [b][J=j>>5][cblk=c>>4][g=(j>>3)&3][ln=c&15][e=j&7] -> attn av load = 1KB coalesced
//   W3v [4][18][256][32] bf16 @ 11 MiB (1152 KiB)  k-major: per-(chunk,ks) 512B coalesced block
//   W3q [4][18][16][32]  bf16 @ +1179648 (72 KiB)
//   W3k [4][18][16][32]  bf16 @ +73728   (72 KiB)

typedef __bf16 bf16;
typedef bf16 bf16x8 __attribute__((ext_vector_type(8)));
typedef float f32x4 __attribute__((ext_vector_type(4)));
typedef unsigned long long ull;

#define DEV static __device__ __forceinline__

DEV f32x4 mfma16(bf16x8 a, bf16x8 b, f32x4 c) {
  return __builtin_amdgcn_mfma_f32_16x16x32_bf16(a, b, c, 0, 0, 0);
}

#define SMBUF 25344   // 3*66*64*2 bytes, one staging buffer (divisible by 128)

// ===================== weight pack (all 3 tensors, one launch) =====================
__global__ void pack_all_kernel(const float* __restrict__ wv, const float* __restrict__ wq,
                                const float* __restrict__ wk, bf16* __restrict__ W3v,
                                bf16* __restrict__ W3q, bf16* __restrict__ W3k) {
  int idx = blockIdx.x * 256 + threadIdx.x;
  if (idx >= 663552) return;
  const float* src;
  bf16* dst;
  int rel, O;
  if (idx < 589824)      { src = wv; dst = W3v; rel = idx; O = 256; }
  else if (idx < 626688) { src = wq; dst = W3q; rel = idx - 589824; O = 16; }
  else                   { src = wk; dst = W3k; rel = idx - 626688; O = 16; }
  int o = rel / 2304, r = rel - o * 2304;
  int ci = r / 9, tap = r - ci * 9;
  int chunk = ci >> 6, c6 = ci & 63;
  int ks = (tap << 1) + (c6 >> 5), j = c6 & 31;
  dst[((chunk * 18 + ks) * O + o) * 32 + j] = (bf16)src[rel];
}

// ===================== conv staging, split for software pipelining (T14) ==========
// stage_load: issue 12 float4 global loads into regs (latency hides under MFMA phase).
// stage_write: bf16-convert + b64 LDS writes into [dh][wHalo][cl] swizzled tile.
DEV void stage_load(float4* xv, const float* __restrict__ img, int b, int h, int ci0, int t) {
  const int wg = t & 15, clq = t >> 4;
#pragma unroll
  for (int dh = 0; dh < 3; ++dh) {
    int hh = h + dh - 1;
    bool ok = (hh >= 0) && (hh < 64);
#pragma unroll
    for (int cc = 0; cc < 4; ++cc) {
      float4 v = make_float4(0.f, 0.f, 0.f, 0.f);
      if (ok) v = *(const float4*)&img[((((size_t)b << 8) + ci0 + (clq << 2) + cc) * 64 + hh) * 64 + (wg << 2)];
      xv[dh * 4 + cc] = v;
    }
  }
}

DEV void stage_write(char* smc, const float4* xv, int t) {
  if (t < 96) {   // halo zeros (wH = 0 and 65), b64 granularity
    int dh = t >> 5, r = t & 31;
    int wH = (r & 16) ? 65 : 0, cq = r & 15;
    *(ull*)(smc + ((((dh * 66 + wH) << 7) + (cq << 3)) ^ ((wH & 7) << 4))) = 0ull;
  }
  const int wg = t & 15, clq = t >> 4;
#pragma unroll
  for (int dh = 0; dh < 3; ++dh) {
    const float4 a = xv[dh * 4 + 0], b4 = xv[dh * 4 + 1], c4 = xv[dh * 4 + 2], d4 = xv[dh * 4 + 3];
    const float ax[4] = {a.x, a.y, a.z, a.w};
    const float bx[4] = {b4.x, b4.y, b4.z, b4.w};
    const float cx[4] = {c4.x, c4.y, c4.z, c4.w};
    const float dx[4] = {d4.x, d4.y, d4.z, d4.w};
#pragma unroll
    for (int q4 = 0; q4 < 4; ++q4) {
      int wH = (wg << 2) + q4 + 1;
      union { bf16 h4[4]; ull v; } pk;
      pk.h4[0] = (bf16)ax[q4]; pk.h4[1] = (bf16)bx[q4];
      pk.h4[2] = (bf16)cx[q4]; pk.h4[3] = (bf16)dx[q4];
      *(ull*)(smc + ((((dh * 66 + wH) << 7) + (clq << 3)) ^ ((wH & 7) << 4))) = pk.v;
    }
  }
}

// ===================== conv q + k fused (O=16), pipelined staging =====================
__global__ __launch_bounds__(256) void conv_qk_kernel(
    const float* __restrict__ x, const float* __restrict__ y,
    const bf16* __restrict__ W3q, const bf16* __restrict__ W3k,
    const float* __restrict__ bq, const float* __restrict__ bk,
    bf16* __restrict__ qT, bf16* __restrict__ kT) {
  __shared__ __align__(16) char smc[2 * SMBUF];
  const int mode = blockIdx.x >> 8;       // 0=q, 1=k
  const float* img = mode ? y : x;
  const bf16* W3 = mode ? W3k : W3q;
  const float* bias = mode ? bk : bq;
  const int bi = blockIdx.x & 255;
  const int t = threadIdx.x;
  const int lane = t & 63, wv = t >> 6;
  const int g = lane >> 4, ln = lane & 15;
  const int b = bi >> 6;
  const int h = bi & 63;
  f32x4 acc = {0.f, 0.f, 0.f, 0.f};
  float4 xv[12];
  stage_load(xv, img, b, h, 0, t);
  stage_write(smc, xv, t);
  __syncthreads();
  for (int chunk = 0; chunk < 4; ++chunk) {
    char* cur = smc + (chunk & 1) * SMBUF;
    if (chunk < 3) stage_load(xv, img, b, h, (chunk + 1) << 6, t);   // hide under MFMA
#pragma unroll
    for (int ks = 0; ks < 18; ++ks) {
      const int tap = ks >> 1, clb = (ks & 1) << 5;
      const int kh = tap / 3, kw = tap - kh * 3;
      const int wH = (wv << 4) + ln + kw;
      uint32_t bo = ((((kh * 66 + wH) << 6) + clb + (g << 3)) << 1) ^ ((wH & 7) << 4);
      bf16x8 bfr = *(const bf16x8*)(cur + bo);
      bf16x8 afr = *(const bf16x8*)&W3[(size_t)((chunk * 18 + ks) * 16 + ln) * 32 + (g << 3)];
      acc = mfma16(afr, bfr, acc);
    }
    if (chunk < 3) stage_write(smc + ((chunk + 1) & 1) * SMBUF, xv, t);
    __syncthreads();
  }
  const int p = (h << 6) + (wv << 4) + ln;
#pragma unroll
  for (int r = 0; r < 4; ++r) {
    int o = (g << 2) + r;
    float val = acc[r] + bias[o];
    if (mode == 0) {
      val *= 1.4426950408889634f;              // log2(e): softmax via exp2
      bf16* drow = qT + (((size_t)b << 12) + p) * 64;
      bf16 hi = (bf16)val;
      drow[o] = hi;
      drow[16 + o] = hi;                       // B1 = [qh|qh]
      drow[32 + o] = (bf16)(val - (float)hi);  // B2 = [ql|0]
      drow[48 + o] = (bf16)0.f;
    } else {
      bf16* drow = kT + (((size_t)b << 12) + p) * 32;
      bf16 hi = (bf16)val;
      drow[o] = hi;                            // A = [kh|kl]
      drow[16 + o] = (bf16)(val - (float)hi);
    }
  }
}

// ===================== conv v (O=256) -> VF fragment layout, pipelined staging =======
__global__ __launch_bounds__(256) void conv_v_kernel(
    const float* __restrict__ img, const bf16* __restrict__ W3,
    const float* __restrict__ bias, bf16* __restrict__ VF) {
  __shared__ __align__(16) char smc[2 * SMBUF];
  const int t = threadIdx.x;
  const int lane = t & 63, wv = t >> 6;
  const int g = lane >> 4, ln = lane & 15;
  const int raw = blockIdx.x;
  const int b = raw >> 7;
  const int h = (raw >> 1) & 63;
  const int oh = raw & 1;
  const int obase = (oh << 7) + (wv << 5);
  f32x4 acc[2][4];
#pragma unroll
  for (int of = 0; of < 2; ++of)
#pragma unroll
    for (int wf = 0; wf < 4; ++wf) acc[of][wf] = (f32x4){0.f, 0.f, 0.f, 0.f};
  float4 xv[12];
  stage_load(xv, img, b, h, 0, t);
  stage_write(smc, xv, t);
  __syncthreads();
  for (int chunk = 0; chunk < 4; ++chunk) {
    char* cur = smc + (chunk & 1) * SMBUF;
    if (chunk < 3) stage_load(xv, img, b, h, (chunk + 1) << 6, t);   // hide under MFMA
#pragma unroll
    for (int ks = 0; ks < 18; ++ks) {
      const int tap = ks >> 1, clb = (ks & 1) << 5;
      const int kh = tap / 3, kw = tap - kh * 3;
      bf16x8 bfr[4];
#pragma unroll
      for (int wf = 0; wf < 4; ++wf) {
        int wH = (wf << 4) + ln + kw;
        uint32_t bo = ((((kh * 66 + wH) << 6) + clb + (g << 3)) << 1) ^ ((wH & 7) << 4);
        bfr[wf] = *(const bf16x8*)(cur + bo);
      }
#pragma unroll
      for (int of = 0; of < 2; ++of) {
        bf16x8 afr = *(const bf16x8*)&W3[(size_t)((chunk * 18 + ks) * 256 + obase + (of << 4) + ln) * 32 + (g << 3)];
#pragma unroll
        for (int wf = 0; wf < 4; ++wf) acc[of][wf] = mfma16(afr, bfr[wf], acc[of][wf]);
      }
    }
    if (chunk < 3) stage_write(smc + ((chunk + 1) & 1) * SMBUF, xv, t);
    __syncthreads();
  }
  // epilogue -> VF[b][J][cblk][g][ln][e]
#pragma unroll
  for (int of = 0; of < 2; ++of) {
    const int cblk = (obase >> 4) + of;
#pragma unroll
    for (int r = 0; r < 4; ++r) {
      int c = obase + (of << 4) + (g << 2) + r;
      int lnv = c & 15;
      float bvv = bias[c];
#pragma unroll
      for (int wf = 0; wf < 4; ++wf) {
        int p = (h << 6) + (wf << 4) + ln;
        int J = p >> 5, gv = (p >> 3) & 3, e = p & 7;
        VF[(((size_t)(((b << 7) + J) << 4) + cblk) << 9) + (gv << 7) + (lnv << 3) + e] =
            (bf16)(acc[of][wf][r] + bvv);
      }
    }
  }
}

// ===================== attention =====================
// r14 structure (measured ~45-55 µs in r16): producer/consumer, __syncthreads dbuf,
// launch_bounds(512,2), VF fragment-ordered V -> 1KB coalesced av loads.
// grid 256 = (b, it 0..63), i-tile 64, 8 waves. Waves 0-3 producers (f=wv): QK from
// K-LDS, exp2, P->LDS(dbuf), K staging. Waves 4-7 consumers (64 ch): ping-pong V
// prefetch, PV over 4 f. Raw exp2 (no max). batch -> XCD pair {b, b+4}.
__global__ __launch_bounds__(512, 2) void attn_kernel(
    const bf16* __restrict__ qT, const bf16* __restrict__ kT,
    const bf16* __restrict__ VF, float* __restrict__ outp) {
  __shared__ __align__(16) char Klds[2 * 4096];   // [buf][row 64][64B] swizzled
  __shared__ __align__(16) char Plds[2 * 8192];   // [buf][f 4][ln 16][128B] swizzled
  __shared__ float lsumS[4][16];
  const int raw = blockIdx.x;          // 256
  const int b  = raw & 3;              // batch -> XCD pair {b, b+4}
  const int it = raw >> 2;             // 0..63
  const int i0 = it << 6;
  const int t = threadIdx.x;
  const int lane = t & 63, wv = t >> 6;
  const int g = lane >> 4, ln = lane & 15;
  const bool prod = (wv < 4);
  const int f = wv & 3;
  const int cb = f << 6;               // consumer: 64-channel base
  const int cblk0 = f << 2;            // = cb >> 4

  const char* kTb = (const char*)kT + (((size_t)b << 12) << 6);  // 64B rows
  const char* vfb = (const char*)VF + ((size_t)b << 21);         // b * 2MB

  // producer state
  bf16x8 bq1 = {}, bq2 = {};
  if (prod) {
    const bf16* qrow = &qT[(((size_t)b << 12) + i0 + (f << 4) + ln) * 64];
    bq1 = *(const bf16x8*)&qrow[g << 3];
    bq2 = *(const bf16x8*)&qrow[32 + (g << 3)];
  }
  float lsum = 0.f;
  const int krow = t >> 2, kc = t & 3;   // K-stage map (producers: t 0..255)
  const uint32_t kwoff = ((uint32_t)krow << 6) + ((uint32_t)(kc ^ (krow & 3)) << 4);

  // consumer state
  f32x4 acc[4][4];   // [cf][f]
#pragma unroll
  for (int cf = 0; cf < 4; ++cf)
#pragma unroll
    for (int ff = 0; ff < 4; ++ff) acc[cf][ff] = (f32x4){0.f, 0.f, 0.f, 0.f};
  bf16x8 avA[8], avB[8];   // ping-pong V prefetch [ks*4+cf]; static idx via unroll

  // prologue: producers stage K(0) -> buf0
  if (prod)
    *(f32x4*)(Klds + kwoff) = *(const f32x4*)(kTb + ((size_t)krow << 6) + (kc << 4));
  __syncthreads();

  for (int m = 0; m < 32; ++m) {
    const int jtA = m << 1;           // even jt
    // ---------- sub-iter A ----------
    if (prod) {
      f32x4 s[4];
#pragma unroll
      for (int jf = 0; jf < 4; ++jf) {
        const int row = (jf << 4) + ln;
        bf16x8 ak = *(const bf16x8*)(Klds + ((uint32_t)row << 6) + ((uint32_t)(g ^ (row & 3)) << 4));
        f32x4 z = {0.f, 0.f, 0.f, 0.f};
        s[jf] = mfma16(ak, bq2, mfma16(ak, bq1, z));
      }
#pragma unroll
      for (int jf = 0; jf < 4; ++jf) {
        union { bf16 h[4]; ull v; } pk;
#pragma unroll
        for (int r = 0; r < 4; ++r) {
          float pv = __builtin_amdgcn_exp2f(s[jf][r]);
          lsum += pv;
          pk.h[r] = (bf16)pv;
        }
        uint32_t bo = (((uint32_t)f << 11) + ((uint32_t)ln << 7) + (jf << 5) + (g << 3)) ^ ((ln & 7) << 4);
        *(ull*)(Plds + bo) = pk.v;            // P buf0
      }
      // stage K(jtA+1) -> buf1
      *(f32x4*)(Klds + 4096 + kwoff) =
          *(const f32x4*)(kTb + ((size_t)(((jtA + 1) << 6) + krow) << 6) + (kc << 4));
    } else {
#pragma unroll
      for (int ks = 0; ks < 2; ++ks)
#pragma unroll
        for (int cf = 0; cf < 4; ++cf)
          avB[ks * 4 + cf] = *(const bf16x8*)(vfb +
              ((size_t)(((jtA << 1) + ks) * 16 + cblk0 + cf) << 10) + (lane << 4));
      if (m > 0) {   // PV(jtA-1): P buf1, V in avA
        __builtin_amdgcn_s_setprio(1);
#pragma unroll
        for (int ks = 0; ks < 2; ++ks) {
          bf16x8 bp[4];
#pragma unroll
          for (int ff = 0; ff < 4; ++ff) {
            uint32_t bo = (8192u + ((uint32_t)ff << 11) + ((uint32_t)ln << 7) + (ks << 6) + (g << 4)) ^ ((ln & 7) << 4);
            bp[ff] = *(const bf16x8*)(Plds + bo);
          }
#pragma unroll
          for (int cf = 0; cf < 4; ++cf)
#pragma unroll
            for (int ff = 0; ff < 4; ++ff)
              acc[cf][ff] = mfma16(avA[ks * 4 + cf], bp[ff], acc[cf][ff]);
        }
        __builtin_amdgcn_s_setprio(0);
      }
    }
    __syncthreads();
    // ---------- sub-iter B ----------
    const int jtB = jtA + 1;          // odd jt
    if (prod) {
      f32x4 s[4];
#pragma unroll
      for (int jf = 0; jf < 4; ++jf) {
        const int row = (jf << 4) + ln;
        bf16x8 ak = *(const bf16x8*)(Klds + 4096 + ((uint32_t)row << 6) + ((uint32_t)(g ^ (row & 3)) << 4));
        f32x4 z = {0.f, 0.f, 0.f, 0.f};
        s[jf] = mfma16(ak, bq2, mfma16(ak, bq1, z));
      }
#pragma unroll
      for (int jf = 0; jf < 4; ++jf) {
        union { bf16 h[4]; ull v; } pk;
#pragma unroll
        for (int r = 0; r < 4; ++r) {
          float pv = __builtin_amdgcn_exp2f(s[jf][r]);
          lsum += pv;
          pk.h[r] = (bf16)pv;
        }
        uint32_t bo = (8192u + ((uint32_t)f << 11) + ((uint32_t)ln << 7) + (jf << 5) + (g << 3)) ^ ((ln & 7) << 4);
        *(ull*)(Plds + bo) = pk.v;            // P buf1
      }
      if (m < 31)   // stage K(jtB+1) -> buf0
        *(f32x4*)(Klds + kwoff) =
            *(const f32x4*)(kTb + ((size_t)(((jtB + 1) << 6) + krow) << 6) + (kc << 4));
    } else {
#pragma unroll
      for (int ks = 0; ks < 2; ++ks)
#pragma unroll
        for (int cf = 0; cf < 4; ++cf)
          avA[ks * 4 + cf] = *(const bf16x8*)(vfb +
              ((size_t)(((jtB << 1) + ks) * 16 + cblk0 + cf) << 10) + (lane << 4));
      // PV(jtA): P buf0, V in avB
      __builtin_amdgcn_s_setprio(1);
#pragma unroll
      for (int ks = 0; ks < 2; ++ks) {
        bf16x8 bp[4];
#pragma unroll
        for (int ff = 0; ff < 4; ++ff) {
          uint32_t bo = (((uint32_t)ff << 11) + ((uint32_t)ln << 7) + (ks << 6) + (g << 4)) ^ ((ln & 7) << 4);
          bp[ff] = *(const bf16x8*)(Plds + bo);
        }
#pragma unroll
        for (int cf = 0; cf < 4; ++cf)
#pragma unroll
          for (int ff = 0; ff < 4; ++ff)
            acc[cf][ff] = mfma16(avB[ks * 4 + cf], bp[ff], acc[cf][ff]);
      }
      __builtin_amdgcn_s_setprio(0);
    }
    __syncthreads();
  }
  // epilogue: producers publish lsum; consumers final PV(63) (P buf1, avA)
  if (prod) {
    float l = lsum;
    l += __shfl_xor(l, 16, 64);
    l += __shfl_xor(l, 32, 64);
    if (g == 0) lsumS[f][ln] = l;
  } else {
#pragma unroll
    for (int ks = 0; ks < 2; ++ks) {
      bf16x8 bp[4];
#pragma unroll
      for (int ff = 0; ff < 4; ++ff) {
        uint32_t bo = (8192u + ((uint32_t)ff << 11) + ((uint32_t)ln << 7) + (ks << 6) + (g << 4)) ^ ((ln & 7) << 4);
        bp[ff] = *(const bf16x8*)(Plds + bo);
      }
#pragma unroll
      for (int cf = 0; cf < 4; ++cf)
#pragma unroll
        for (int ff = 0; ff < 4; ++ff)
          acc[cf][ff] = mfma16(avA[ks * 4 + cf], bp[ff], acc[cf][ff]);
    }
  }
  __syncthreads();
  if (!prod) {
#pragma unroll
    for (int ff = 0; ff < 4; ++ff) {
      float rdiv = 1.f / lsumS[ff][ln];
      const int i = i0 + (ff << 4) + ln;
#pragma unroll
      for (int cf = 0; cf < 4; ++cf)
#pragma unroll
        for (int r = 0; r < 4; ++r) {
          int c = cb + (cf << 4) + (g << 2) + r;
          outp[(((size_t)b << 8) + c) * 4096 + i] = acc[cf][ff][r] * rdiv;
        }
    }
  }
}

// ===================== launch =====================
extern "C" void kernel_launch(void* const* d_in, const int* in_sizes, int n_in,
                              void* d_out, int out_size, void* d_ws, size_t ws_size,
                              hipStream_t stream) {
  const float* x  = (const float*)d_in[0];
  const float* y  = (const float*)d_in[1];
  const float* wq = (const float*)d_in[2];
  const float* bq = (const float*)d_in[3];
  const float* wk = (const float*)d_in[4];
  const float* bk = (const float*)d_in[5];
  const float* wv = (const float*)d_in[6];
  const float* bv = (const float*)d_in[7];
  float* out = (float*)d_out;

  char* ws = (char*)d_ws;
  bf16* qT  = (bf16*)(ws);
  bf16* kT  = (bf16*)(ws + (2u << 20));
  bf16* VF  = (bf16*)(ws + (3u << 20));
  bf16* W3v = (bf16*)(ws + (11u << 20));
  bf16* W3q = (bf16*)(ws + (11u << 20) + 1179648u);
  bf16* W3k = (bf16*)(ws + (11u << 20) + 1179648u + 73728u);

  pack_all_kernel<<<2592, 256, 0, stream>>>(wv, wq, wk, W3v, W3q, W3k);
  conv_qk_kernel<<<512, 256, 0, stream>>>(x, y, W3q, W3k, bq, bk, qT, kT);
  conv_v_kernel<<<512, 256, 0, stream>>>(y, W3v, bv, VF);
  attn_kernel<<<256, 512, 0, stream>>>(qT, kT, VF, out);
}

// Round 18
// 132.855 us; speedup vs baseline: 2.6473x; 1.3221x over previous
//
#include <hip/hip_runtime.h>
#include <stdint.h>

// B=4, C=256, H=W=64, N=4096, CQK=16, Ktot=C*9=2304
// ws layout:
//   qT  [4][4096][64] bf16   @ 0     (2 MiB)  slots0-31=[qh|qh], 32-63=[ql|0], q pre-scaled by log2(e)
//   kT  [4][4096][32] bf16   @ 2 MiB (1 MiB)  slots0-15=kh, 16-31=kl (residual)
//   VF  [4][128][16][512] bf16 @ 3 MiB (8 MiB) V in MFMA-fragment order:
//        [b][J=j>>5][cblk=c>>4][g=(j>>3)&3][ln=c&15][e=j&7] -> attn av load = 1KB coalesced
//   W3v [4][18][256][32] bf16 @ 11 MiB (1152 KiB)  k-major: per-(chunk,ks) 512B coalesced block
//   W3q [4][18][16][32]  bf16 @ +1179648 (72 KiB)
//   W3k [4][18][16][32]  bf16 @ +73728   (72 KiB)

typedef __bf16 bf16;
typedef bf16 bf16x8 __attribute__((ext_vector_type(8)));
typedef float f32x4 __attribute__((ext_vector_type(4)));
typedef unsigned long long ull;

#define DEV static __device__ __forceinline__

DEV f32x4 mfma16(bf16x8 a, bf16x8 b, f32x4 c) {
  return __builtin_amdgcn_mfma_f32_16x16x32_bf16(a, b, c, 0, 0, 0);
}

#define SMBUF 25344   // 3*66*64*2 bytes, one staging buffer (divisible by 128)

// ===================== weight pack (all 3 tensors, one launch) =====================
__global__ void pack_all_kernel(const float* __restrict__ wv, const float* __restrict__ wq,
                                const float* __restrict__ wk, bf16* __restrict__ W3v,
                                bf16* __restrict__ W3q, bf16* __restrict__ W3k) {
  int idx = blockIdx.x * 256 + threadIdx.x;
  if (idx >= 663552) return;
  const float* src;
  bf16* dst;
  int rel, O;
  if (idx < 589824)      { src = wv; dst = W3v; rel = idx; O = 256; }
  else if (idx < 626688) { src = wq; dst = W3q; rel = idx - 589824; O = 16; }
  else                   { src = wk; dst = W3k; rel = idx - 626688; O = 16; }
  int o = rel / 2304, r = rel - o * 2304;
  int ci = r / 9, tap = r - ci * 9;
  int chunk = ci >> 6, c6 = ci & 63;
  int ks = (tap << 1) + (c6 >> 5), j = c6 & 31;
  dst[((chunk * 18 + ks) * O + o) * 32 + j] = (bf16)src[rel];
}

// ===================== conv staging, split load/write ==========
DEV void stage_load(float4* xv, const float* __restrict__ img, int b, int h, int ci0, int t) {
  const int wg = t & 15, clq = t >> 4;
#pragma unroll
  for (int dh = 0; dh < 3; ++dh) {
    int hh = h + dh - 1;
    bool ok = (hh >= 0) && (hh < 64);
#pragma unroll
    for (int cc = 0; cc < 4; ++cc) {
      float4 v = make_float4(0.f, 0.f, 0.f, 0.f);
      if (ok) v = *(const float4*)&img[((((size_t)b << 8) + ci0 + (clq << 2) + cc) * 64 + hh) * 64 + (wg << 2)];
      xv[dh * 4 + cc] = v;
    }
  }
}

DEV void stage_write(char* smc, const float4* xv, int t) {
  if (t < 96) {   // halo zeros (wH = 0 and 65), b64 granularity
    int dh = t >> 5, r = t & 31;
    int wH = (r & 16) ? 65 : 0, cq = r & 15;
    *(ull*)(smc + ((((dh * 66 + wH) << 7) + (cq << 3)) ^ ((wH & 7) << 4))) = 0ull;
  }
  const int wg = t & 15, clq = t >> 4;
#pragma unroll
  for (int dh = 0; dh < 3; ++dh) {
    const float4 a = xv[dh * 4 + 0], b4 = xv[dh * 4 + 1], c4 = xv[dh * 4 + 2], d4 = xv[dh * 4 + 3];
    const float ax[4] = {a.x, a.y, a.z, a.w};
    const float bx[4] = {b4.x, b4.y, b4.z, b4.w};
    const float cx[4] = {c4.x, c4.y, c4.z, c4.w};
    const float dx[4] = {d4.x, d4.y, d4.z, d4.w};
#pragma unroll
    for (int q4 = 0; q4 < 4; ++q4) {
      int wH = (wg << 2) + q4 + 1;
      union { bf16 h4[4]; ull v; } pk;
      pk.h4[0] = (bf16)ax[q4]; pk.h4[1] = (bf16)bx[q4];
      pk.h4[2] = (bf16)cx[q4]; pk.h4[3] = (bf16)dx[q4];
      *(ull*)(smc + ((((dh * 66 + wH) << 7) + (clq << 3)) ^ ((wH & 7) << 4))) = pk.v;
    }
  }
}

// ===================== conv q + k fused (O=16), pipelined staging =====================
__global__ __launch_bounds__(256) void conv_qk_kernel(
    const float* __restrict__ x, const float* __restrict__ y,
    const bf16* __restrict__ W3q, const bf16* __restrict__ W3k,
    const float* __restrict__ bq, const float* __restrict__ bk,
    bf16* __restrict__ qT, bf16* __restrict__ kT) {
  __shared__ __align__(16) char smc[2 * SMBUF];
  const int mode = blockIdx.x >> 8;       // 0=q, 1=k
  const float* img = mode ? y : x;
  const bf16* W3 = mode ? W3k : W3q;
  const float* bias = mode ? bk : bq;
  const int bi = blockIdx.x & 255;
  const int t = threadIdx.x;
  const int lane = t & 63, wv = t >> 6;
  const int g = lane >> 4, ln = lane & 15;
  const int b = bi >> 6;
  const int h = bi & 63;
  f32x4 acc = {0.f, 0.f, 0.f, 0.f};
  float4 xv[12];
  stage_load(xv, img, b, h, 0, t);
  stage_write(smc, xv, t);
  __syncthreads();
  for (int chunk = 0; chunk < 4; ++chunk) {
    char* cur = smc + (chunk & 1) * SMBUF;
    if (chunk < 3) stage_load(xv, img, b, h, (chunk + 1) << 6, t);   // hide under MFMA
#pragma unroll
    for (int ks = 0; ks < 18; ++ks) {
      const int tap = ks >> 1, clb = (ks & 1) << 5;
      const int kh = tap / 3, kw = tap - kh * 3;
      const int wH = (wv << 4) + ln + kw;
      uint32_t bo = ((((kh * 66 + wH) << 6) + clb + (g << 3)) << 1) ^ ((wH & 7) << 4);
      bf16x8 bfr = *(const bf16x8*)(cur + bo);
      bf16x8 afr = *(const bf16x8*)&W3[(size_t)((chunk * 18 + ks) * 16 + ln) * 32 + (g << 3)];
      acc = mfma16(afr, bfr, acc);
    }
    if (chunk < 3) stage_write(smc + ((chunk + 1) & 1) * SMBUF, xv, t);
    __syncthreads();
  }
  const int p = (h << 6) + (wv << 4) + ln;
#pragma unroll
  for (int r = 0; r < 4; ++r) {
    int o = (g << 2) + r;
    float val = acc[r] + bias[o];
    if (mode == 0) {
      val *= 1.4426950408889634f;              // log2(e): softmax via exp2
      bf16* drow = qT + (((size_t)b << 12) + p) * 64;
      bf16 hi = (bf16)val;
      drow[o] = hi;
      drow[16 + o] = hi;                       // B1 = [qh|qh]
      drow[32 + o] = (bf16)(val - (float)hi);  // B2 = [ql|0]
      drow[48 + o] = (bf16)0.f;
    } else {
      bf16* drow = kT + (((size_t)b << 12) + p) * 32;
      bf16 hi = (bf16)val;
      drow[o] = hi;                            // A = [kh|kl]
      drow[16 + o] = (bf16)(val - (float)hi);
    }
  }
}

// ===================== conv v (O=256) -> VF, oh-split x4 for occupancy =============
// r17 PMC: conv_v latency-bound, all pipes <8%, only 2 blocks/CU (grid 512). Fix: grid
// 1024 = b(4) x h(64) x oh(4); block owns 64 o (wave: 16). Single-buffer staging
// (25.3KB -> 4 blocks/CU, 16 waves/CU = 2x TLP); per-CU MFMA/W3 traffic unchanged;
// input restaged 2x more (L3-resident, cheap). acc[4] -> VGPR ~90.
__global__ __launch_bounds__(256) void conv_v_kernel(
    const float* __restrict__ img, const bf16* __restrict__ W3,
    const float* __restrict__ bias, bf16* __restrict__ VF) {
  __shared__ __align__(16) char smc[SMBUF];
  const int t = threadIdx.x;
  const int lane = t & 63, wv = t >> 6;
  const int g = lane >> 4, ln = lane & 15;
  const int raw = blockIdx.x;          // 1024 = b(4) x h(64) x oh(4)
  const int b = raw >> 8;
  const int h = (raw >> 2) & 63;
  const int oh = raw & 3;
  const int obase = (oh << 6) + (wv << 4);   // wave owns 16 out-channels
  f32x4 acc[4];
#pragma unroll
  for (int wf = 0; wf < 4; ++wf) acc[wf] = (f32x4){0.f, 0.f, 0.f, 0.f};
  float4 xv[12];
  for (int chunk = 0; chunk < 4; ++chunk) {
    stage_load(xv, img, b, h, chunk << 6, t);
    __syncthreads();   // readers of previous chunk done
    stage_write(smc, xv, t);
    __syncthreads();   // staging visible
#pragma unroll
    for (int ks = 0; ks < 18; ++ks) {
      const int tap = ks >> 1, clb = (ks & 1) << 5;
      const int kh = tap / 3, kw = tap - kh * 3;
      bf16x8 afr = *(const bf16x8*)&W3[(size_t)((chunk * 18 + ks) * 256 + obase + ln) * 32 + (g << 3)];
#pragma unroll
      for (int wf = 0; wf < 4; ++wf) {
        int wH = (wf << 4) + ln + kw;
        uint32_t bo = ((((kh * 66 + wH) << 6) + clb + (g << 3)) << 1) ^ ((wH & 7) << 4);
        bf16x8 bfr = *(const bf16x8*)(smc + bo);
        acc[wf] = mfma16(afr, bfr, acc[wf]);
      }
    }
  }
  // epilogue -> VF[b][J][cblk][g][ln][e]
  const int cblk = obase >> 4;
#pragma unroll
  for (int r = 0; r < 4; ++r) {
    int c = obase + (g << 2) + r;
    int lnv = c & 15;
    float bvv = bias[c];
#pragma unroll
    for (int wf = 0; wf < 4; ++wf) {
      int p = (h << 6) + (wf << 4) + ln;
      int J = p >> 5, gv = (p >> 3) & 3, e = p & 7;
      VF[(((size_t)(((b << 7) + J) << 4) + cblk) << 9) + (gv << 7) + (lnv << 3) + e] =
          (bf16)(acc[wf][r] + bvv);
    }
  }
}

// ===================== attention =====================
// r14 structure (measured ~45-55 µs): producer/consumer, __syncthreads dbuf,
// launch_bounds(512,2), VF fragment-ordered V -> 1KB coalesced av loads.
// grid 256 = (b, it 0..63), i-tile 64, 8 waves. Waves 0-3 producers (f=wv): QK from
// K-LDS, exp2, P->LDS(dbuf), K staging. Waves 4-7 consumers (64 ch): ping-pong V
// prefetch, PV over 4 f. Raw exp2 (no max). batch -> XCD pair {b, b+4}.
__global__ __launch_bounds__(512, 2) void attn_kernel(
    const bf16* __restrict__ qT, const bf16* __restrict__ kT,
    const bf16* __restrict__ VF, float* __restrict__ outp) {
  __shared__ __align__(16) char Klds[2 * 4096];   // [buf][row 64][64B] swizzled
  __shared__ __align__(16) char Plds[2 * 8192];   // [buf][f 4][ln 16][128B] swizzled
  __shared__ float lsumS[4][16];
  const int raw = blockIdx.x;          // 256
  const int b  = raw & 3;              // batch -> XCD pair {b, b+4}
  const int it = raw >> 2;             // 0..63
  const int i0 = it << 6;
  const int t = threadIdx.x;
  const int lane = t & 63, wv = t >> 6;
  const int g = lane >> 4, ln = lane & 15;
  const bool prod = (wv < 4);
  const int f = wv & 3;
  const int cb = f << 6;               // consumer: 64-channel base
  const int cblk0 = f << 2;            // = cb >> 4

  const char* kTb = (const char*)kT + (((size_t)b << 12) << 6);  // 64B rows
  const char* vfb = (const char*)VF + ((size_t)b << 21);         // b * 2MB

  // producer state
  bf16x8 bq1 = {}, bq2 = {};
  if (prod) {
    const bf16* qrow = &qT[(((size_t)b << 12) + i0 + (f << 4) + ln) * 64];
    bq1 = *(const bf16x8*)&qrow[g << 3];
    bq2 = *(const bf16x8*)&qrow[32 + (g << 3)];
  }
  float lsum = 0.f;
  const int krow = t >> 2, kc = t & 3;   // K-stage map (producers: t 0..255)
  const uint32_t kwoff = ((uint32_t)krow << 6) + ((uint32_t)(kc ^ (krow & 3)) << 4);

  // consumer state
  f32x4 acc[4][4];   // [cf][f]
#pragma unroll
  for (int cf = 0; cf < 4; ++cf)
#pragma unroll
    for (int ff = 0; ff < 4; ++ff) acc[cf][ff] = (f32x4){0.f, 0.f, 0.f, 0.f};
  bf16x8 avA[8], avB[8];   // ping-pong V prefetch [ks*4+cf]; static idx via unroll

  // prologue: producers stage K(0) -> buf0
  if (prod)
    *(f32x4*)(Klds + kwoff) = *(const f32x4*)(kTb + ((size_t)krow << 6) + (kc << 4));
  __syncthreads();

  for (int m = 0; m < 32; ++m) {
    const int jtA = m << 1;           // even jt
    // ---------- sub-iter A ----------
    if (prod) {
      f32x4 s[4];
#pragma unroll
      for (int jf = 0; jf < 4; ++jf) {
        const int row = (jf << 4) + ln;
        bf16x8 ak = *(const bf16x8*)(Klds + ((uint32_t)row << 6) + ((uint32_t)(g ^ (row & 3)) << 4));
        f32x4 z = {0.f, 0.f, 0.f, 0.f};
        s[jf] = mfma16(ak, bq2, mfma16(ak, bq1, z));
      }
#pragma unroll
      for (int jf = 0; jf < 4; ++jf) {
        union { bf16 h[4]; ull v; } pk;
#pragma unroll
        for (int r = 0; r < 4; ++r) {
          float pv = __builtin_amdgcn_exp2f(s[jf][r]);
          lsum += pv;
          pk.h[r] = (bf16)pv;
        }
        uint32_t bo = (((uint32_t)f << 11) + ((uint32_t)ln << 7) + (jf << 5) + (g << 3)) ^ ((ln & 7) << 4);
        *(ull*)(Plds + bo) = pk.v;            // P buf0
      }
      // stage K(jtA+1) -> buf1
      *(f32x4*)(Klds + 4096 + kwoff) =
          *(const f32x4*)(kTb + ((size_t)(((jtA + 1) << 6) + krow) << 6) + (kc << 4));
    } else {
#pragma unroll
      for (int ks = 0; ks < 2; ++ks)
#pragma unroll
        for (int cf = 0; cf < 4; ++cf)
          avB[ks * 4 + cf] = *(const bf16x8*)(vfb +
              ((size_t)(((jtA << 1) + ks) * 16 + cblk0 + cf) << 10) + (lane << 4));
      if (m > 0) {   // PV(jtA-1): P buf1, V in avA
        __builtin_amdgcn_s_setprio(1);
#pragma unroll
        for (int ks = 0; ks < 2; ++ks) {
          bf16x8 bp[4];
#pragma unroll
          for (int ff = 0; ff < 4; ++ff) {
            uint32_t bo = (8192u + ((uint32_t)ff << 11) + ((uint32_t)ln << 7) + (ks << 6) + (g << 4)) ^ ((ln & 7) << 4);
            bp[ff] = *(const bf16x8*)(Plds + bo);
          }
#pragma unroll
          for (int cf = 0; cf < 4; ++cf)
#pragma unroll
            for (int ff = 0; ff < 4; ++ff)
              acc[cf][ff] = mfma16(avA[ks * 4 + cf], bp[ff], acc[cf][ff]);
        }
        __builtin_amdgcn_s_setprio(0);
      }
    }
    __syncthreads();
    // ---------- sub-iter B ----------
    const int jtB = jtA + 1;          // odd jt
    if (prod) {
      f32x4 s[4];
#pragma unroll
      for (int jf = 0; jf < 4; ++jf) {
        const int row = (jf << 4) + ln;
        bf16x8 ak = *(const bf16x8*)(Klds + 4096 + ((uint32_t)row << 6) + ((uint32_t)(g ^ (row & 3)) << 4));
        f32x4 z = {0.f, 0.f, 0.f, 0.f};
        s[jf] = mfma16(ak, bq2, mfma16(ak, bq1, z));
      }
#pragma unroll
      for (int jf = 0; jf < 4; ++jf) {
        union { bf16 h[4]; ull v; } pk;
#pragma unroll
        for (int r = 0; r < 4; ++r) {
          float pv = __builtin_amdgcn_exp2f(s[jf][r]);
          lsum += pv;
          pk.h[r] = (bf16)pv;
        }
        uint32_t bo = (8192u + ((uint32_t)f << 11) + ((uint32_t)ln << 7) + (jf << 5) + (g << 3)) ^ ((ln & 7) << 4);
        *(ull*)(Plds + bo) = pk.v;            // P buf1
      }
      if (m < 31)   // stage K(jtB+1) -> buf0
        *(f32x4*)(Klds + kwoff) =
            *(const f32x4*)(kTb + ((size_t)(((jtB + 1) << 6) + krow) << 6) + (kc << 4));
    } else {
#pragma unroll
      for (int ks = 0; ks < 2; ++ks)
#pragma unroll
        for (int cf = 0; cf < 4; ++cf)
          avA[ks * 4 + cf] = *(const bf16x8*)(vfb +
              ((size_t)(((jtB << 1) + ks) * 16 + cblk0 + cf) << 10) + (lane << 4));
      // PV(jtA): P buf0, V in avB
      __builtin_amdgcn_s_setprio(1);
#pragma unroll
      for (int ks = 0; ks < 2; ++ks) {
        bf16x8 bp[4];
#pragma unroll
        for (int ff = 0; ff < 4; ++ff) {
          uint32_t bo = (((uint32_t)ff << 11) + ((uint32_t)ln << 7) + (ks << 6) + (g << 4)) ^ ((ln & 7) << 4);
          bp[ff] = *(const bf16x8*)(Plds + bo);
        }
#pragma unroll
        for (int cf = 0; cf < 4; ++cf)
#pragma unroll
          for (int ff = 0; ff < 4; ++ff)
            acc[cf][ff] = mfma16(avB[ks * 4 + cf], bp[ff], acc[cf][ff]);
      }
      __builtin_amdgcn_s_setprio(0);
    }
    __syncthreads();
  }
  // epilogue: producers publish lsum; consumers final PV(63) (P buf1, avA)
  if (prod) {
    float l = lsum;
    l += __shfl_xor(l, 16, 64);
    l += __shfl_xor(l, 32, 64);
    if (g == 0) lsumS[f][ln] = l;
  } else {
#pragma unroll
    for (int ks = 0; ks < 2; ++ks) {
      bf16x8 bp[4];
#pragma unroll
      for (int ff = 0; ff < 4; ++ff) {
        uint32_t bo = (8192u + ((uint32_t)ff << 11) + ((uint32_t)ln << 7) + (ks << 6) + (g << 4)) ^ ((ln & 7) << 4);
        bp[ff] = *(const bf16x8*)(Plds + bo);
      }
#pragma unroll
      for (int cf = 0; cf < 4; ++cf)
#pragma unroll
        for (int ff = 0; ff < 4; ++ff)
          acc[cf][ff] = mfma16(avA[ks * 4 + cf], bp[ff], acc[cf][ff]);
    }
  }
  __syncthreads();
  if (!prod) {
#pragma unroll
    for (int ff = 0; ff < 4; ++ff) {
      float rdiv = 1.f / lsumS[ff][ln];
      const int i = i0 + (ff << 4) + ln;
#pragma unroll
      for (int cf = 0; cf < 4; ++cf)
#pragma unroll
        for (int r = 0; r < 4; ++r) {
          int c = cb + (cf << 4) + (g << 2) + r;
          outp[(((size_t)b << 8) + c) * 4096 + i] = acc[cf][ff][r] * rdiv;
        }
    }
  }
}

// ===================== launch =====================
extern "C" void kernel_launch(void* const* d_in, const int* in_sizes, int n_in,
                              void* d_out, int out_size, void* d_ws, size_t ws_size,
                              hipStream_t stream) {
  const float* x  = (const float*)d_in[0];
  const float* y  = (const float*)d_in[1];
  const float* wq = (const float*)d_in[2];
  const float* bq = (const float*)d_in[3];
  const float* wk = (const float*)d_in[4];
  const float* bk = (const float*)d_in[5];
  const float* wv = (const float*)d_in[6];
  const float* bv = (const float*)d_in[7];
  float* out = (float*)d_out;

  char* ws = (char*)d_ws;
  bf16* qT  = (bf16*)(ws);
  bf16* kT  = (bf16*)(ws + (2u << 20));
  bf16* VF  = (bf16*)(ws + (3u << 20));
  bf16* W3v = (bf16*)(ws + (11u << 20));
  bf16* W3q = (bf16*)(ws + (11u << 20) + 1179648u);
  bf16* W3k = (bf16*)(ws + (11u << 20) + 1179648u + 73728u);

  pack_all_kernel<<<2592, 256, 0, stream>>>(wv, wq, wk, W3v, W3q, W3k);
  conv_qk_kernel<<<512, 256, 0, stream>>>(x, y, W3q, W3k, bq, bk, qT, kT);
  conv_v_kernel<<<1024, 256, 0, stream>>>(y, W3v, bv, VF);
  attn_kernel<<<256, 512, 0, stream>>>(qT, kT, VF, out);
}